// Round 3
// baseline (127.127 us; speedup 1.0000x reference)
//
#include <hip/hip_runtime.h>

#define BATCH 16
#define SEQ   4096
#define DIM   64
#define WIN   512

constexpr int BM = 128;       // q rows per block
constexpr int BN = 128;       // keys per tile (doubled: fewer rounds/barriers)
constexpr int NTHREADS = 512; // 8 waves
constexpr int KS = DIM + 8;   // Ksh row stride (f16) -> b128 reads conflict-free
constexpr int VS = BN + 4;    // Vsh row stride (f16), 264B rows keep b64 aligned
constexpr int OS = DIM + 4;   // Osh row stride (f32 elems)
constexpr int KBYTES   = BN * KS * 2;        // 18432
constexpr int VBYTES   = DIM * VS * 2;       // 16896
constexpr int BUFBYTES = KBYTES + VBYTES;    // 35328
constexpr int SMEMBYTES = 2 * BUFBYTES;      // 70656 (dynamic LDS, 2 blocks/CU)

// fold softmax scale and log2(e) into Q so p = exp2(s - m)
constexpr float QSCALE  = 0.125f * 1.44269504088896340736f;
constexpr float MASKVAL = -3.0e38f;   // << m_run init (-1e30) so masked lanes give p=0
constexpr float DEFER_THR = 8.0f;     // T13: tolerate p up to 2^8 before rescaling O

typedef _Float16 f16x2 __attribute__((ext_vector_type(2)));
typedef _Float16 f16x4 __attribute__((ext_vector_type(4)));
typedef _Float16 f16x8 __attribute__((ext_vector_type(8)));
typedef float    f32x4 __attribute__((ext_vector_type(4)));

__device__ __forceinline__ f16x2 pk2(float a, float b) {
    return __builtin_bit_cast(f16x2, __builtin_amdgcn_cvt_pkrtz(a, b));
}

// per-thread prefetch registers for one 128-key tile (2 key rows x 2 halves)
struct Pref {
    float4 k0, k1, k2, k3;
    float4 v0, v1, v2, v3;
};

__device__ __forceinline__ void load_tile(Pref& p, const float* __restrict__ kb,
                                          const float* __restrict__ vb,
                                          int kbase, int row2, int c4) {
    const size_t g0 = (size_t)(kbase + row2) * DIM + c4;
    p.k0 = *(const float4*)&kb[g0];
    p.k1 = *(const float4*)&kb[g0 + DIM];
    p.v0 = *(const float4*)&vb[g0];
    p.v1 = *(const float4*)&vb[g0 + DIM];
    const size_t g1 = g0 + (size_t)64 * DIM;
    p.k2 = *(const float4*)&kb[g1];
    p.k3 = *(const float4*)&kb[g1 + DIM];
    p.v2 = *(const float4*)&vb[g1];
    p.v3 = *(const float4*)&vb[g1 + DIM];
}

__device__ __forceinline__ void stage_tile(char* __restrict__ buf, const Pref& p,
                                           int row2, int c4) {
    _Float16* Ksh = (_Float16*)buf;
    _Float16* Vsh = (_Float16*)(buf + KBYTES);
    union { f16x4 v; f16x2 h[2]; } uk;
    uk.h[0] = pk2(p.k0.x, p.k0.y); uk.h[1] = pk2(p.k0.z, p.k0.w);
    *(f16x4*)&Ksh[(row2 + 0) * KS + c4] = uk.v;
    uk.h[0] = pk2(p.k1.x, p.k1.y); uk.h[1] = pk2(p.k1.z, p.k1.w);
    *(f16x4*)&Ksh[(row2 + 1) * KS + c4] = uk.v;
    uk.h[0] = pk2(p.k2.x, p.k2.y); uk.h[1] = pk2(p.k2.z, p.k2.w);
    *(f16x4*)&Ksh[(row2 + 64) * KS + c4] = uk.v;
    uk.h[0] = pk2(p.k3.x, p.k3.y); uk.h[1] = pk2(p.k3.z, p.k3.w);
    *(f16x4*)&Ksh[(row2 + 65) * KS + c4] = uk.v;
    // V transposed: adjacent key pair -> one 4B f16x2 store
    *(f16x2*)&Vsh[(c4 + 0) * VS + row2] = pk2(p.v0.x, p.v1.x);
    *(f16x2*)&Vsh[(c4 + 1) * VS + row2] = pk2(p.v0.y, p.v1.y);
    *(f16x2*)&Vsh[(c4 + 2) * VS + row2] = pk2(p.v0.z, p.v1.z);
    *(f16x2*)&Vsh[(c4 + 3) * VS + row2] = pk2(p.v0.w, p.v1.w);
    *(f16x2*)&Vsh[(c4 + 0) * VS + row2 + 64] = pk2(p.v2.x, p.v3.x);
    *(f16x2*)&Vsh[(c4 + 1) * VS + row2 + 64] = pk2(p.v2.y, p.v3.y);
    *(f16x2*)&Vsh[(c4 + 2) * VS + row2 + 64] = pk2(p.v2.z, p.v3.z);
    *(f16x2*)&Vsh[(c4 + 3) * VS + row2 + 64] = pk2(p.v2.w, p.v3.w);
}

__global__ __launch_bounds__(NTHREADS, 4)   // cap VGPR<=128 -> 2 blocks/CU resident
void swa_kernel(const float* __restrict__ qg, const float* __restrict__ kg,
                const float* __restrict__ vg, float* __restrict__ outg) {
    // dynamic LDS: 2 x { Ksh [128][72] f16 | Vsh [64][132] f16 }; epilogue Osh overlays
    extern __shared__ __align__(16) char smem[];
    float* Osh = (float*)smem;

    const int tid  = threadIdx.x;
    const int lane = tid & 63;
    const int wave = tid >> 6;     // 0..7
    const int lr   = lane & 15;
    const int quad = lane >> 4;

    // chunked XCD swizzle (kept: FETCH is at compulsory minimum with it)
    static_assert(SEQ / BM == 32 && BATCH == 16, "swizzle assumes 512 blocks");
    const int lin    = blockIdx.x + (SEQ / BM) * blockIdx.y;  // 0..511
    const int xcd    = lin & 7;
    const int slot   = lin >> 3;
    const int member = slot & 3;
    const int gchunk = (slot >> 2) * 8 + xcd;  // bijective
    const int b      = gchunk >> 3;
    const int qblk   = (gchunk & 7) * 4 + member;

    const int qrow0 = qblk * BM;
    const int wr0   = qrow0 + wave * 16;
    const int q     = wr0 + lr;          // this lane's q column (S^T layout)

    const float* qb = qg + (size_t)b * SEQ * DIM;
    const float* kb = kg + (size_t)b * SEQ * DIM;
    const float* vb = vg + (size_t)b * SEQ * DIM;
    float*       ob = outg + (size_t)b * SEQ * DIM;

    // staging thread->slot map: two adjacent key rows per thread, x2 halves
    const int row2 = (tid >> 4) * 2;      // 0,2,...,62
    const int c4   = (tid & 15) * 4;      // 0..60

    // ---- Q B-frags straight from global into registers ----
    const float* qp = qb + (size_t)q * DIM + quad * 8;
    const float4 a0 = *(const float4*)(qp + 0);
    const float4 a1 = *(const float4*)(qp + 4);
    const float4 a2 = *(const float4*)(qp + 32);
    const float4 a3 = *(const float4*)(qp + 36);
    union { f16x8 v; f16x2 h[4]; } uq0, uq1;
    uq0.h[0] = pk2(a0.x * QSCALE, a0.y * QSCALE);
    uq0.h[1] = pk2(a0.z * QSCALE, a0.w * QSCALE);
    uq0.h[2] = pk2(a1.x * QSCALE, a1.y * QSCALE);
    uq0.h[3] = pk2(a1.z * QSCALE, a1.w * QSCALE);
    uq1.h[0] = pk2(a2.x * QSCALE, a2.y * QSCALE);
    uq1.h[1] = pk2(a2.z * QSCALE, a2.w * QSCALE);
    uq1.h[2] = pk2(a3.x * QSCALE, a3.y * QSCALE);
    uq1.h[3] = pk2(a3.z * QSCALE, a3.w * QSCALE);
    const f16x8 qf0 = uq0.v, qf1 = uq1.v;

    f32x4 o[4];
    #pragma unroll
    for (int mi = 0; mi < 4; ++mi) o[mi] = (f32x4){0.f, 0.f, 0.f, 0.f};
    float m_run = -1e30f, l_run = 0.f;

    const int T0 = (qrow0 > (WIN - 1)) ? (qrow0 - (WIN - 1)) >> 7 : 0;
    const int T1 = (qrow0 + BM - 1) >> 7;   // == qblk

    // ---- prologue: stage tile T0 into buffer 0 ----
    Pref pf;
    load_tile(pf, kb, vb, T0 * BN, row2, c4);
    stage_tile(smem, pf, row2, c4);
    __syncthreads();

    for (int t = T0; t <= T1; ++t) {
        const int cb = (t - T0) & 1;
        const _Float16* Kc = (const _Float16*)(smem + cb * BUFBYTES);
        const _Float16* Vc = (const _Float16*)(smem + cb * BUFBYTES + KBYTES);
        const bool have_next = (t < T1);

        if (have_next) load_tile(pf, kb, vb, (t + 1) * BN, row2, c4);
        // pin the prefetch ISSUE point: nothing (incl. these loads) may cross
        __builtin_amdgcn_sched_barrier(0);

        const int kbase = t * BN;

        // ---- S^T = K * Q^T : 8 key m-tiles x 2 k-chunks of 32 ----
        f32x4 sc[8];
        #pragma unroll
        for (int mt = 0; mt < 8; ++mt) {
            const f16x8 kf0 = *(const f16x8*)&Kc[(mt * 16 + lr) * KS + quad * 8];
            const f16x8 kf1 = *(const f16x8*)&Kc[(mt * 16 + lr) * KS + 32 + quad * 8];
            f32x4 s = (f32x4){0.f, 0.f, 0.f, 0.f};
            s = __builtin_amdgcn_mfma_f32_16x16x32_f16(kf0, qf0, s, 0, 0, 0);
            s = __builtin_amdgcn_mfma_f32_16x16x32_f16(kf1, qf1, s, 0, 0, 0);
            sc[mt] = s;
        }

        // ---- mask only on window-edge rounds (first & last; wave-uniform) ----
        const bool edge = (kbase < wr0 + 15 - (WIN - 1)) || (kbase + BN - 1 > wr0);
        if (edge) {
            #pragma unroll
            for (int mt = 0; mt < 8; ++mt) {
                #pragma unroll
                for (int r = 0; r < 4; ++r) {
                    const int key = kbase + mt * 16 + quad * 4 + r;
                    sc[mt][r] = ((unsigned)(q - key) < (unsigned)WIN) ? sc[mt][r] : MASKVAL;
                }
            }
        }

        // ---- row max: pairwise tree (v_max3-fusable), then cross-quad ----
        float pmt[8];
        #pragma unroll
        for (int mt = 0; mt < 8; ++mt)
            pmt[mt] = fmaxf(fmaxf(sc[mt][0], sc[mt][1]), fmaxf(sc[mt][2], sc[mt][3]));
        float pm = fmaxf(fmaxf(fmaxf(pmt[0], pmt[1]), fmaxf(pmt[2], pmt[3])),
                         fmaxf(fmaxf(pmt[4], pmt[5]), fmaxf(pmt[6], pmt[7])));
        pm = fmaxf(pm, __shfl_xor(pm, 16));
        pm = fmaxf(pm, __shfl_xor(pm, 32));

        // ---- T13 defer-rescale ----
        if (__any(pm > m_run + DEFER_THR)) {
            const float mn    = fmaxf(m_run, pm);
            const float alpha = exp2f(m_run - mn);
            m_run = mn;
            l_run *= alpha;
            #pragma unroll
            for (int mi = 0; mi < 4; ++mi) o[mi] = o[mi] * alpha;
        }

        f16x4 pb[8];
        float ls = 0.f;
        #pragma unroll
        for (int nt = 0; nt < 8; ++nt) {
            const float p0 = exp2f(sc[nt][0] - m_run);
            const float p1 = exp2f(sc[nt][1] - m_run);
            const float p2 = exp2f(sc[nt][2] - m_run);
            const float p3 = exp2f(sc[nt][3] - m_run);
            ls += (p0 + p1) + (p2 + p3);
            union { f16x4 v; f16x2 h[2]; } up;
            up.h[0] = pk2(p0, p1);
            up.h[1] = pk2(p2, p3);
            pb[nt] = up.v;
        }
        l_run += ls;

        // ---- O^T += V^T * P^T ----
        #pragma unroll
        for (int nt = 0; nt < 8; ++nt) {
            #pragma unroll
            for (int mi = 0; mi < 4; ++mi) {
                const f16x4 vf = *(const f16x4*)&Vc[(mi * 16 + lr) * VS + nt * 16 + quad * 4];
                o[mi] = __builtin_amdgcn_mfma_f32_16x16x16f16(vf, pb[nt], o[mi], 0, 0, 0);
            }
        }

        // ---- stage t+1 into alternate buffer; ONE barrier per round ----
        // (compute read cb, stage writes cb^1 -> disjoint; barrier publishes
        //  cb^1 for next round AND proves cb free for next round's stage)
        if (have_next) stage_tile(smem + (cb ^ 1) * BUFBYTES, pf, row2, c4);
        __syncthreads();
    }

    // ---- epilogue: l reduce across quads, normalize, transpose via LDS, store ----
    l_run += __shfl_xor(l_run, 16);
    l_run += __shfl_xor(l_run, 32);
    const float inv = 1.0f / l_run;

    float* Ow = Osh + wave * 16 * OS;   // per-wave private 16 x OS region
    #pragma unroll
    for (int mi = 0; mi < 4; ++mi) {
        float4 st;
        st.x = o[mi][0] * inv; st.y = o[mi][1] * inv;
        st.z = o[mi][2] * inv; st.w = o[mi][3] * inv;
        *(float4*)&Ow[lr * OS + mi * 16 + quad * 4] = st;
    }
    #pragma unroll
    for (int j = 0; j < 4; ++j) {
        const int qq = quad + 4 * j;
        const int d4 = lr * 4;
        const float4 vst = *(const float4*)&Ow[qq * OS + d4];
        *(float4*)&ob[(size_t)(wr0 + qq) * DIM + d4] = vst;
    }
}

extern "C" void kernel_launch(void* const* d_in, const int* in_sizes, int n_in,
                              void* d_out, int out_size, void* d_ws, size_t ws_size,
                              hipStream_t stream) {
    (void)in_sizes; (void)n_in; (void)out_size; (void)d_ws; (void)ws_size;
    static bool inited = false;
    if (!inited) {
        hipFuncSetAttribute((const void*)swa_kernel,
                            hipFuncAttributeMaxDynamicSharedMemorySize, SMEMBYTES);
        inited = true;
    }
    const float* q = (const float*)d_in[0];
    const float* k = (const float*)d_in[1];
    const float* v = (const float*)d_in[2];
    float* out = (float*)d_out;
    dim3 grid(SEQ / BM, BATCH);
    swa_kernel<<<grid, dim3(NTHREADS), SMEMBYTES, stream>>>(q, k, v, out);
}

// Round 4
// 120.138 us; speedup vs baseline: 1.0582x; 1.0582x over previous
//
#include <hip/hip_runtime.h>

#define BATCH 16
#define SEQ   4096
#define DIM   64
#define WIN   512

constexpr int BM = 128;       // q rows per block
constexpr int BN = 128;       // keys per tile
constexpr int NTHREADS = 512; // 8 waves
constexpr int KS = DIM + 8;   // Ksh row stride (f16) -> b128 reads ~conflict-free
constexpr int VS = BN + 4;    // Vsh row stride (f16); row byte-stride %8==0 for b64
constexpr int OS = DIM + 4;   // Osh row stride (f32 elems)
constexpr int KBYTES   = BN * KS * 2;        // 18432
constexpr int VBYTES   = DIM * VS * 2;       // 16896
constexpr int BUFBYTES = KBYTES + VBYTES;    // 35328
constexpr int SMEMBYTES = 2 * BUFBYTES;      // 70656 (dynamic LDS, 2 blocks/CU)

// fold softmax scale and log2(e) into Q so p = exp2(s - m)
constexpr float QSCALE  = 0.125f * 1.44269504088896340736f;
constexpr float MASKVAL = -3.0e38f;   // << m_run init (-1e30) so masked lanes give p=0
constexpr float DEFER_THR = 8.0f;     // T13: tolerate p up to 2^8 before rescaling O

typedef _Float16 f16x2 __attribute__((ext_vector_type(2)));
typedef _Float16 f16x4 __attribute__((ext_vector_type(4)));
typedef _Float16 f16x8 __attribute__((ext_vector_type(8)));
typedef float    f32x4 __attribute__((ext_vector_type(4)));

__device__ __forceinline__ f16x2 pk2(float a, float b) {
    return __builtin_bit_cast(f16x2, __builtin_amdgcn_cvt_pkrtz(a, b));
}

// per-thread prefetch registers for one 128-key tile (2 key rows x 2 halves)
struct Pref {
    float4 k0, k1, k2, k3;
    float4 v0, v1, v2, v3;
};

__device__ __forceinline__ void load_tile(Pref& p, const float* __restrict__ kb,
                                          const float* __restrict__ vb,
                                          int kbase, int row2, int c4) {
    const size_t g0 = (size_t)(kbase + row2) * DIM + c4;
    p.k0 = *(const float4*)&kb[g0];
    p.k1 = *(const float4*)&kb[g0 + DIM];
    p.v0 = *(const float4*)&vb[g0];
    p.v1 = *(const float4*)&vb[g0 + DIM];
    const size_t g1 = g0 + (size_t)64 * DIM;
    p.k2 = *(const float4*)&kb[g1];
    p.k3 = *(const float4*)&kb[g1 + DIM];
    p.v2 = *(const float4*)&vb[g1];
    p.v3 = *(const float4*)&vb[g1 + DIM];
}

__device__ __forceinline__ void stage_tile(char* __restrict__ buf, const Pref& p,
                                           int row2, int c4) {
    _Float16* Ksh = (_Float16*)buf;
    _Float16* Vsh = (_Float16*)(buf + KBYTES);
    union { f16x4 v; f16x2 h[2]; } uk;
    uk.h[0] = pk2(p.k0.x, p.k0.y); uk.h[1] = pk2(p.k0.z, p.k0.w);
    *(f16x4*)&Ksh[(row2 + 0) * KS + c4] = uk.v;
    uk.h[0] = pk2(p.k1.x, p.k1.y); uk.h[1] = pk2(p.k1.z, p.k1.w);
    *(f16x4*)&Ksh[(row2 + 1) * KS + c4] = uk.v;
    uk.h[0] = pk2(p.k2.x, p.k2.y); uk.h[1] = pk2(p.k2.z, p.k2.w);
    *(f16x4*)&Ksh[(row2 + 64) * KS + c4] = uk.v;
    uk.h[0] = pk2(p.k3.x, p.k3.y); uk.h[1] = pk2(p.k3.z, p.k3.w);
    *(f16x4*)&Ksh[(row2 + 65) * KS + c4] = uk.v;
    // V transposed: adjacent key pair -> one 4B f16x2 store
    *(f16x2*)&Vsh[(c4 + 0) * VS + row2] = pk2(p.v0.x, p.v1.x);
    *(f16x2*)&Vsh[(c4 + 1) * VS + row2] = pk2(p.v0.y, p.v1.y);
    *(f16x2*)&Vsh[(c4 + 2) * VS + row2] = pk2(p.v0.z, p.v1.z);
    *(f16x2*)&Vsh[(c4 + 3) * VS + row2] = pk2(p.v0.w, p.v1.w);
    *(f16x2*)&Vsh[(c4 + 0) * VS + row2 + 64] = pk2(p.v2.x, p.v3.x);
    *(f16x2*)&Vsh[(c4 + 1) * VS + row2 + 64] = pk2(p.v2.y, p.v3.y);
    *(f16x2*)&Vsh[(c4 + 2) * VS + row2 + 64] = pk2(p.v2.z, p.v3.z);
    *(f16x2*)&Vsh[(c4 + 3) * VS + row2 + 64] = pk2(p.v2.w, p.v3.w);
}

// (512, 2): under blocks/CU semantics -> 16 waves/CU -> 128 VGPR cap;
// under waves/EU semantics -> 256 cap. Either way no spill (need ~100).
__global__ __launch_bounds__(NTHREADS, 2)
void swa_kernel(const float* __restrict__ qg, const float* __restrict__ kg,
                const float* __restrict__ vg, float* __restrict__ outg) {
    // dynamic LDS: 2 x { Ksh [128][72] f16 | Vsh [64][132] f16 }; epilogue Osh overlays
    extern __shared__ __align__(16) char smem[];
    float* Osh = (float*)smem;

    const int tid  = threadIdx.x;
    const int lane = tid & 63;
    const int wave = tid >> 6;     // 0..7
    const int lr   = lane & 15;
    const int quad = lane >> 4;

    // chunked XCD swizzle: 4 consecutive qblks of one batch co-resident per XCD
    static_assert(SEQ / BM == 32 && BATCH == 16, "swizzle assumes 512 blocks");
    const int lin    = blockIdx.x + (SEQ / BM) * blockIdx.y;  // 0..511
    const int xcd    = lin & 7;
    const int slot   = lin >> 3;
    const int member = slot & 3;
    const int gchunk = (slot >> 2) * 8 + xcd;  // bijective
    const int b      = gchunk >> 3;
    const int qblk   = (gchunk & 7) * 4 + member;

    const int qrow0 = qblk * BM;
    const int wr0   = qrow0 + wave * 16;
    const int q     = wr0 + lr;          // this lane's q column (S^T layout)

    const float* qb = qg + (size_t)b * SEQ * DIM;
    const float* kb = kg + (size_t)b * SEQ * DIM;
    const float* vb = vg + (size_t)b * SEQ * DIM;
    float*       ob = outg + (size_t)b * SEQ * DIM;

    // staging thread->slot map: two adjacent key rows per thread, x2 halves
    const int row2 = (tid >> 4) * 2;      // 0,2,...,62
    const int c4   = (tid & 15) * 4;      // 0..60

    // ---- Q B-frags straight from global into registers ----
    const float* qp = qb + (size_t)q * DIM + quad * 8;
    const float4 a0 = *(const float4*)(qp + 0);
    const float4 a1 = *(const float4*)(qp + 4);
    const float4 a2 = *(const float4*)(qp + 32);
    const float4 a3 = *(const float4*)(qp + 36);
    union { f16x8 v; f16x2 h[4]; } uq0, uq1;
    uq0.h[0] = pk2(a0.x * QSCALE, a0.y * QSCALE);
    uq0.h[1] = pk2(a0.z * QSCALE, a0.w * QSCALE);
    uq0.h[2] = pk2(a1.x * QSCALE, a1.y * QSCALE);
    uq0.h[3] = pk2(a1.z * QSCALE, a1.w * QSCALE);
    uq1.h[0] = pk2(a2.x * QSCALE, a2.y * QSCALE);
    uq1.h[1] = pk2(a2.z * QSCALE, a2.w * QSCALE);
    uq1.h[2] = pk2(a3.x * QSCALE, a3.y * QSCALE);
    uq1.h[3] = pk2(a3.z * QSCALE, a3.w * QSCALE);
    const f16x8 qf0 = uq0.v, qf1 = uq1.v;

    f32x4 o[4];
    #pragma unroll
    for (int mi = 0; mi < 4; ++mi) o[mi] = (f32x4){0.f, 0.f, 0.f, 0.f};
    float m_run = -1e30f, l_run = 0.f;

    const int T0 = (qrow0 > (WIN - 1)) ? (qrow0 - (WIN - 1)) >> 7 : 0;
    const int T1 = (qrow0 + BM - 1) >> 7;   // == qblk

    // ---- prologue: stage tile T0 into buffer 0 ----
    Pref pf;
    load_tile(pf, kb, vb, T0 * BN, row2, c4);
    stage_tile(smem, pf, row2, c4);
    __syncthreads();

    for (int t = T0; t <= T1; ++t) {
        const int cb = (t - T0) & 1;
        const _Float16* Kc = (const _Float16*)(smem + cb * BUFBYTES);
        const _Float16* Vc = (const _Float16*)(smem + cb * BUFBYTES + KBYTES);
        const bool have_next = (t < T1);

        if (have_next) load_tile(pf, kb, vb, (t + 1) * BN, row2, c4);
        // pin the prefetch ISSUE point: nothing (incl. these loads) may cross
        __builtin_amdgcn_sched_barrier(0);

        const int kbase = t * BN;
        // wave-uniform active m-tile range: window keys [wr0-511, wr0+15]
        const int u    = (wr0 - kbase) >> 4;        // >= 0 (kbase <= wr0 always)
        const int mtlo = (u - 32 > 0) ? u - 32 : 0;
        const int mthi = (u < 7) ? u : 7;

        if (mtlo <= mthi) {
            // ---- S^T = K * Q^T : active key m-tiles x 2 k-chunks of 32 ----
            f32x4 sc[8];
            #pragma unroll
            for (int mt = 0; mt < 8; ++mt) {
                if (mt >= mtlo && mt <= mthi) {
                    const f16x8 kf0 = *(const f16x8*)&Kc[(mt * 16 + lr) * KS + quad * 8];
                    const f16x8 kf1 = *(const f16x8*)&Kc[(mt * 16 + lr) * KS + 32 + quad * 8];
                    f32x4 s = (f32x4){0.f, 0.f, 0.f, 0.f};
                    s = __builtin_amdgcn_mfma_f32_16x16x32_f16(kf0, qf0, s, 0, 0, 0);
                    s = __builtin_amdgcn_mfma_f32_16x16x32_f16(kf1, qf1, s, 0, 0, 0);
                    sc[mt] = s;
                }
            }

            // ---- mask only on window-edge rounds (wave-uniform) ----
            const bool edge = (kbase + mtlo * 16 < wr0 + 15 - (WIN - 1)) ||
                              (kbase + mthi * 16 + 15 > wr0);
            if (edge) {
                #pragma unroll
                for (int mt = 0; mt < 8; ++mt) {
                    if (mt >= mtlo && mt <= mthi) {
                        #pragma unroll
                        for (int r = 0; r < 4; ++r) {
                            const int key = kbase + mt * 16 + quad * 4 + r;
                            sc[mt][r] = ((unsigned)(q - key) < (unsigned)WIN) ? sc[mt][r] : MASKVAL;
                        }
                    }
                }
            }

            // ---- row max over active tiles, then cross-quad ----
            float pm = MASKVAL;
            #pragma unroll
            for (int mt = 0; mt < 8; ++mt) {
                if (mt >= mtlo && mt <= mthi) {
                    pm = fmaxf(pm, fmaxf(fmaxf(sc[mt][0], sc[mt][1]),
                                         fmaxf(sc[mt][2], sc[mt][3])));
                }
            }
            pm = fmaxf(pm, __shfl_xor(pm, 16));
            pm = fmaxf(pm, __shfl_xor(pm, 32));

            // ---- T13 defer-rescale ----
            if (__any(pm > m_run + DEFER_THR)) {
                const float mn    = fmaxf(m_run, pm);
                const float alpha = exp2f(m_run - mn);
                m_run = mn;
                l_run *= alpha;
                #pragma unroll
                for (int mi = 0; mi < 4; ++mi) o[mi] = o[mi] * alpha;
            }

            f16x4 pb[8];
            float ls = 0.f;
            #pragma unroll
            for (int nt = 0; nt < 8; ++nt) {
                if (nt >= mtlo && nt <= mthi) {
                    const float p0 = exp2f(sc[nt][0] - m_run);
                    const float p1 = exp2f(sc[nt][1] - m_run);
                    const float p2 = exp2f(sc[nt][2] - m_run);
                    const float p3 = exp2f(sc[nt][3] - m_run);
                    ls += (p0 + p1) + (p2 + p3);
                    union { f16x4 v; f16x2 h[2]; } up;
                    up.h[0] = pk2(p0, p1);
                    up.h[1] = pk2(p2, p3);
                    pb[nt] = up.v;
                }
            }
            l_run += ls;

            // ---- O^T += V^T * P^T over active tiles ----
            #pragma unroll
            for (int nt = 0; nt < 8; ++nt) {
                if (nt >= mtlo && nt <= mthi) {
                    #pragma unroll
                    for (int mi = 0; mi < 4; ++mi) {
                        const f16x4 vf = *(const f16x4*)&Vc[(mi * 16 + lr) * VS + nt * 16 + quad * 4];
                        o[mi] = __builtin_amdgcn_mfma_f32_16x16x16f16(vf, pb[nt], o[mi], 0, 0, 0);
                    }
                }
            }
        }

        // ---- stage t+1 into alternate buffer; ONE barrier per round ----
        if (have_next) stage_tile(smem + (cb ^ 1) * BUFBYTES, pf, row2, c4);
        __syncthreads();
    }

    // ---- epilogue: l reduce across quads, normalize, transpose via LDS, store ----
    l_run += __shfl_xor(l_run, 16);
    l_run += __shfl_xor(l_run, 32);
    const float inv = 1.0f / l_run;

    float* Ow = Osh + wave * 16 * OS;   // per-wave private 16 x OS region
    #pragma unroll
    for (int mi = 0; mi < 4; ++mi) {
        float4 st;
        st.x = o[mi][0] * inv; st.y = o[mi][1] * inv;
        st.z = o[mi][2] * inv; st.w = o[mi][3] * inv;
        *(float4*)&Ow[lr * OS + mi * 16 + quad * 4] = st;
    }
    #pragma unroll
    for (int j = 0; j < 4; ++j) {
        const int qq = quad + 4 * j;
        const int d4 = lr * 4;
        const float4 vst = *(const float4*)&Ow[qq * OS + d4];
        *(float4*)&ob[(size_t)(wr0 + qq) * DIM + d4] = vst;
    }
}

extern "C" void kernel_launch(void* const* d_in, const int* in_sizes, int n_in,
                              void* d_out, int out_size, void* d_ws, size_t ws_size,
                              hipStream_t stream) {
    (void)in_sizes; (void)n_in; (void)out_size; (void)d_ws; (void)ws_size;
    static bool inited = false;
    if (!inited) {
        hipFuncSetAttribute((const void*)swa_kernel,
                            hipFuncAttributeMaxDynamicSharedMemorySize, SMEMBYTES);
        inited = true;
    }
    const float* q = (const float*)d_in[0];
    const float* k = (const float*)d_in[1];
    const float* v = (const float*)d_in[2];
    float* out = (float*)d_out;
    dim3 grid(SEQ / BM, BATCH);
    swa_kernel<<<grid, dim3(NTHREADS), SMEMBYTES, stream>>>(q, k, v, out);
}

// Round 5
// 116.071 us; speedup vs baseline: 1.0953x; 1.0350x over previous
//
#include <hip/hip_runtime.h>

#define BATCH 16
#define SEQ   4096
#define DIM   64
#define WIN   512

constexpr int BM = 64;        // q rows per block (4 waves -> small barrier groups)
constexpr int BN = 64;        // keys per tile
constexpr int NTHREADS = 256; // 4 waves
constexpr int KS = DIM + 8;   // Ksh row stride (f16) -> b128 reads ~conflict-free
constexpr int VS = BN + 4;    // Vsh row stride (f16)
constexpr int OS = DIM + 4;   // Osh row stride (f32)
constexpr int KBYTES   = BN * KS * 2;        // 9216
constexpr int VBYTES   = DIM * VS * 2;       // 8704
constexpr int BUFBYTES = KBYTES + VBYTES;    // 17920
constexpr int SMEMBYTES = 2 * BUFBYTES;      // 35840 B -> 4 blocks/CU fit (143KB/160KB)

constexpr float QSCALE  = 0.125f * 1.44269504088896340736f;
constexpr float MASKVAL = -3.0e38f;
constexpr float DEFER_THR = 8.0f;

typedef _Float16 f16x2 __attribute__((ext_vector_type(2)));
typedef _Float16 f16x4 __attribute__((ext_vector_type(4)));
typedef _Float16 f16x8 __attribute__((ext_vector_type(8)));
typedef float    f32x4 __attribute__((ext_vector_type(4)));

__device__ __forceinline__ f16x2 pk2(float a, float b) {
    return __builtin_bit_cast(f16x2, __builtin_amdgcn_cvt_pkrtz(a, b));
}

// per-thread prefetch: 4 adjacent K rows + 4 adjacent V rows, one float4 column chunk
struct Pref {
    float4 k0, k1, k2, k3;
    float4 v0, v1, v2, v3;
};

__device__ __forceinline__ void load_tile(Pref& p, const float* __restrict__ kb,
                                          const float* __restrict__ vb,
                                          int kbase, int row4, int c4) {
    const size_t g = (size_t)(kbase + row4) * DIM + c4;
    p.k0 = *(const float4*)&kb[g + 0 * DIM];
    p.k1 = *(const float4*)&kb[g + 1 * DIM];
    p.k2 = *(const float4*)&kb[g + 2 * DIM];
    p.k3 = *(const float4*)&kb[g + 3 * DIM];
    p.v0 = *(const float4*)&vb[g + 0 * DIM];
    p.v1 = *(const float4*)&vb[g + 1 * DIM];
    p.v2 = *(const float4*)&vb[g + 2 * DIM];
    p.v3 = *(const float4*)&vb[g + 3 * DIM];
}

__device__ __forceinline__ void stage_tile(char* __restrict__ buf, const Pref& p,
                                           int row4, int c4) {
    _Float16* Ksh = (_Float16*)buf;
    _Float16* Vsh = (_Float16*)(buf + KBYTES);
    union { f16x4 v; f16x2 h[2]; } u;
    u.h[0] = pk2(p.k0.x, p.k0.y); u.h[1] = pk2(p.k0.z, p.k0.w);
    *(f16x4*)&Ksh[(row4 + 0) * KS + c4] = u.v;
    u.h[0] = pk2(p.k1.x, p.k1.y); u.h[1] = pk2(p.k1.z, p.k1.w);
    *(f16x4*)&Ksh[(row4 + 1) * KS + c4] = u.v;
    u.h[0] = pk2(p.k2.x, p.k2.y); u.h[1] = pk2(p.k2.z, p.k2.w);
    *(f16x4*)&Ksh[(row4 + 2) * KS + c4] = u.v;
    u.h[0] = pk2(p.k3.x, p.k3.y); u.h[1] = pk2(p.k3.z, p.k3.w);
    *(f16x4*)&Ksh[(row4 + 3) * KS + c4] = u.v;
    // V transposed: 4 adjacent keys at fixed d -> one 8B f16x4 store per d
    const float* f0 = (const float*)&p.v0;
    const float* f1 = (const float*)&p.v1;
    const float* f2 = (const float*)&p.v2;
    const float* f3 = (const float*)&p.v3;
    #pragma unroll
    for (int j = 0; j < 4; ++j) {
        u.h[0] = pk2(f0[j], f1[j]);
        u.h[1] = pk2(f2[j], f3[j]);
        *(f16x4*)&Vsh[(c4 + j) * VS + row4] = u.v;
    }
}

// (256,4): blocks/CU-semantics -> 16 waves/CU (VGPR cap 128); waves/EU-semantics
// -> 4 blocks/CU -> same. Both readings give 4 blocks x 4 waves resident.
__global__ __launch_bounds__(NTHREADS, 4)
void swa_kernel(const float* __restrict__ qg, const float* __restrict__ kg,
                const float* __restrict__ vg, float* __restrict__ outg) {
    // static LDS: 2 x { Ksh [64][72] f16 | Vsh [64][68] f16 }; epilogue Osh overlays
    __shared__ __align__(16) char smem[SMEMBYTES];
    float* Osh = (float*)smem;

    const int tid  = threadIdx.x;
    const int lane = tid & 63;
    const int wave = tid >> 6;     // 0..3
    const int lr   = lane & 15;
    const int quad = lane >> 4;

    // chunked XCD swizzle: 8 consecutive qblks of one batch per XCD chunk
    static_assert(SEQ / BM == 64 && BATCH == 16, "swizzle assumes 1024 blocks");
    const int lin    = blockIdx.x + (SEQ / BM) * blockIdx.y;  // 0..1023
    const int xcd    = lin & 7;
    const int slot   = lin >> 3;           // 0..127
    const int member = slot & 7;           // position in 8-chunk
    const int gchunk = (slot >> 3) * 8 + xcd;   // 0..127, bijective
    const int b      = gchunk >> 3;             // 16 batches
    const int qblk   = (gchunk & 7) * 8 + member;  // 64 qblks

    const int qrow0 = qblk * BM;
    const int wr0   = qrow0 + wave * 16;
    const int q     = wr0 + lr;          // this lane's q column (S^T layout)

    const float* qb = qg + (size_t)b * SEQ * DIM;
    const float* kb = kg + (size_t)b * SEQ * DIM;
    const float* vb = vg + (size_t)b * SEQ * DIM;
    float*       ob = outg + (size_t)b * SEQ * DIM;

    // staging map: 4 adjacent rows per thread, one float4 column chunk
    const int row4 = (tid >> 4) * 4;      // 0,4,...,60
    const int c4   = (tid & 15) * 4;      // 0..60

    // ---- Q B-frags straight from global into registers ----
    const float* qp = qb + (size_t)q * DIM + quad * 8;
    const float4 a0 = *(const float4*)(qp + 0);
    const float4 a1 = *(const float4*)(qp + 4);
    const float4 a2 = *(const float4*)(qp + 32);
    const float4 a3 = *(const float4*)(qp + 36);
    union { f16x8 v; f16x2 h[4]; } uq0, uq1;
    uq0.h[0] = pk2(a0.x * QSCALE, a0.y * QSCALE);
    uq0.h[1] = pk2(a0.z * QSCALE, a0.w * QSCALE);
    uq0.h[2] = pk2(a1.x * QSCALE, a1.y * QSCALE);
    uq0.h[3] = pk2(a1.z * QSCALE, a1.w * QSCALE);
    uq1.h[0] = pk2(a2.x * QSCALE, a2.y * QSCALE);
    uq1.h[1] = pk2(a2.z * QSCALE, a2.w * QSCALE);
    uq1.h[2] = pk2(a3.x * QSCALE, a3.y * QSCALE);
    uq1.h[3] = pk2(a3.z * QSCALE, a3.w * QSCALE);
    const f16x8 qf0 = uq0.v, qf1 = uq1.v;

    f32x4 o[4];
    #pragma unroll
    for (int mi = 0; mi < 4; ++mi) o[mi] = (f32x4){0.f, 0.f, 0.f, 0.f};
    float m_run = -1e30f, l_run = 0.f;

    const int t0 = (qrow0 > (WIN - 1)) ? (qrow0 - (WIN - 1)) >> 6 : 0;
    const int t1 = (qrow0 + BM - 1) >> 6;   // == qblk

    // ---- prologue: stage tile t0 into buffer 0 ----
    Pref pf;
    load_tile(pf, kb, vb, t0 * BN, row4, c4);
    stage_tile(smem, pf, row4, c4);
    __syncthreads();

    for (int t = t0; t <= t1; ++t) {
        const int cb = (t - t0) & 1;
        const _Float16* Kc = (const _Float16*)(smem + cb * BUFBYTES);
        const _Float16* Vc = (const _Float16*)(smem + cb * BUFBYTES + KBYTES);
        const bool have_next = (t < t1);

        if (have_next) load_tile(pf, kb, vb, (t + 1) * BN, row4, c4);
        // pin the prefetch ISSUE point: loads may not sink below this
        __builtin_amdgcn_sched_barrier(0);

        const int kbase = t * BN;
        // wave-uniform active m-tile range within this 64-key tile
        const int u    = (wr0 - kbase) >> 4;        // >= 0
        const int mtlo = (u - 32 > 0) ? u - 32 : 0; // <= 3 always here
        const int mthi = (u < 3) ? u : 3;

        // ---- S^T = K * Q^T over active m-tiles ----
        f32x4 sc[4];
        #pragma unroll
        for (int mt = 0; mt < 4; ++mt) {
            if (mt >= mtlo && mt <= mthi) {
                const f16x8 kf0 = *(const f16x8*)&Kc[(mt * 16 + lr) * KS + quad * 8];
                const f16x8 kf1 = *(const f16x8*)&Kc[(mt * 16 + lr) * KS + 32 + quad * 8];
                f32x4 s = (f32x4){0.f, 0.f, 0.f, 0.f};
                s = __builtin_amdgcn_mfma_f32_16x16x32_f16(kf0, qf0, s, 0, 0, 0);
                s = __builtin_amdgcn_mfma_f32_16x16x32_f16(kf1, qf1, s, 0, 0, 0);
                sc[mt] = s;
            }
        }

        // ---- mask only on window-edge tiles (wave-uniform branch) ----
        const bool edge = (kbase + mtlo * 16 < wr0 + 15 - (WIN - 1)) ||
                          (kbase + mthi * 16 + 15 > wr0);
        if (edge) {
            #pragma unroll
            for (int mt = 0; mt < 4; ++mt) {
                if (mt >= mtlo && mt <= mthi) {
                    #pragma unroll
                    for (int r = 0; r < 4; ++r) {
                        const int key = kbase + mt * 16 + quad * 4 + r;
                        sc[mt][r] = ((unsigned)(q - key) < (unsigned)WIN) ? sc[mt][r] : MASKVAL;
                    }
                }
            }
        }

        // ---- row max over active tiles, then cross-quad ----
        float pm = MASKVAL;
        #pragma unroll
        for (int mt = 0; mt < 4; ++mt) {
            if (mt >= mtlo && mt <= mthi) {
                pm = fmaxf(pm, fmaxf(fmaxf(sc[mt][0], sc[mt][1]),
                                     fmaxf(sc[mt][2], sc[mt][3])));
            }
        }
        pm = fmaxf(pm, __shfl_xor(pm, 16));
        pm = fmaxf(pm, __shfl_xor(pm, 32));

        // ---- T13 defer-rescale ----
        if (__any(pm > m_run + DEFER_THR)) {
            const float mn    = fmaxf(m_run, pm);
            const float alpha = exp2f(m_run - mn);
            m_run = mn;
            l_run *= alpha;
            #pragma unroll
            for (int mi = 0; mi < 4; ++mi) o[mi] = o[mi] * alpha;
        }

        f16x4 pb[4];
        float ls = 0.f;
        #pragma unroll
        for (int nt = 0; nt < 4; ++nt) {
            if (nt >= mtlo && nt <= mthi) {
                const float p0 = exp2f(sc[nt][0] - m_run);
                const float p1 = exp2f(sc[nt][1] - m_run);
                const float p2 = exp2f(sc[nt][2] - m_run);
                const float p3 = exp2f(sc[nt][3] - m_run);
                ls += (p0 + p1) + (p2 + p3);
                union { f16x4 v; f16x2 h[2]; } up;
                up.h[0] = pk2(p0, p1);
                up.h[1] = pk2(p2, p3);
                pb[nt] = up.v;
            }
        }
        l_run += ls;

        // ---- O^T += V^T * P^T over active tiles ----
        #pragma unroll
        for (int nt = 0; nt < 4; ++nt) {
            if (nt >= mtlo && nt <= mthi) {
                #pragma unroll
                for (int mi = 0; mi < 4; ++mi) {
                    const f16x4 vf = *(const f16x4*)&Vc[(mi * 16 + lr) * VS + nt * 16 + quad * 4];
                    o[mi] = __builtin_amdgcn_mfma_f32_16x16x16f16(vf, pb[nt], o[mi], 0, 0, 0);
                }
            }
        }

        // ---- stage t+1 into alternate buffer; ONE barrier per round ----
        if (have_next) stage_tile(smem + (cb ^ 1) * BUFBYTES, pf, row4, c4);
        __syncthreads();
    }

    // ---- epilogue: l reduce across quads, normalize, transpose via LDS, store ----
    l_run += __shfl_xor(l_run, 16);
    l_run += __shfl_xor(l_run, 32);
    const float inv = 1.0f / l_run;

    float* Ow = Osh + wave * 16 * OS;   // per-wave private 16 x OS region
    #pragma unroll
    for (int mi = 0; mi < 4; ++mi) {
        float4 st;
        st.x = o[mi][0] * inv; st.y = o[mi][1] * inv;
        st.z = o[mi][2] * inv; st.w = o[mi][3] * inv;
        *(float4*)&Ow[lr * OS + mi * 16 + quad * 4] = st;
    }
    #pragma unroll
    for (int j = 0; j < 4; ++j) {
        const int qq = quad + 4 * j;
        const int d4 = lr * 4;
        const float4 vst = *(const float4*)&Ow[qq * OS + d4];
        *(float4*)&ob[(size_t)(wr0 + qq) * DIM + d4] = vst;
    }
}

extern "C" void kernel_launch(void* const* d_in, const int* in_sizes, int n_in,
                              void* d_out, int out_size, void* d_ws, size_t ws_size,
                              hipStream_t stream) {
    (void)in_sizes; (void)n_in; (void)out_size; (void)d_ws; (void)ws_size;
    const float* q = (const float*)d_in[0];
    const float* k = (const float*)d_in[1];
    const float* v = (const float*)d_in[2];
    float* out = (float*)d_out;
    dim3 grid(SEQ / BM, BATCH);
    swa_kernel<<<grid, dim3(NTHREADS), 0, stream>>>(q, k, v, out);
}